// Round 1
// baseline (180.714 us; speedup 1.0000x reference)
//
#include <hip/hip_runtime.h>

// ---------- types / helpers ----------
typedef __attribute__((ext_vector_type(8))) short short8;    // 8 x bf16
typedef __attribute__((ext_vector_type(4))) short short4v;   // 4 x bf16
typedef __attribute__((ext_vector_type(4))) float floatx4;   // MFMA acc / 16B fp32
typedef __attribute__((ext_vector_type(4))) unsigned int uint4v;
typedef __attribute__((ext_vector_type(2))) unsigned int uint2v;

__device__ __forceinline__ unsigned short f2bf(float f) {
  unsigned u = __float_as_uint(f);
  u += 0x7FFFu + ((u >> 16) & 1u);
  return (unsigned short)(u >> 16);
}
// two fp32 -> dword [bf(f0)][bf(f1)] (validated R4+)
__device__ __forceinline__ unsigned pack_bf2(float f0, float f1) {
  unsigned a = __float_as_uint(f0) + 0x8000u;
  unsigned b = __float_as_uint(f1) + 0x8000u;
  return __builtin_amdgcn_perm(b, a, 0x07060302u);
}
__device__ __forceinline__ void async16(const unsigned short* g, unsigned short* l) {
  __builtin_amdgcn_global_load_lds(
      (const __attribute__((address_space(1))) unsigned int*)g,
      (__attribute__((address_space(3))) unsigned int*)l, 16, 0, 0);
}

#define B_   2
#define QN_  2048
#define NDS_ 1024
#define H_   16
// 0.125 * log2(e): exp(s/8) == exp2(s * C_SC)
#define C_SC 0.18033688011f

// ---------- prep: fp32 weights -> bf16 transposed (WT[n][k] = W[k][n]) ----------
__global__ __launch_bounds__(256) void prep(
    const float* __restrict__ Wq, const float* __restrict__ Wk,
    const float* __restrict__ Wv, const float* __restrict__ Wo,
    unsigned short* __restrict__ WT) {
  int bid = blockIdx.x;
  int z = bid >> 8, tile = bid & 255;
  const float* W = z == 0 ? Wq : z == 1 ? Wk : z == 2 ? Wv : Wo;
  unsigned short* out = WT + (size_t)z * (1u << 20);
  __shared__ unsigned short tilebuf[64][65];
  int bi = tile >> 4, bj = tile & 15;
  int c = threadIdx.x & 63, r0 = threadIdx.x >> 6;
#pragma unroll
  for (int i = 0; i < 64; i += 4)
    tilebuf[r0 + i][c] = f2bf(W[(size_t)(bi * 64 + r0 + i) * 1024 + bj * 64 + c]);
  __syncthreads();
#pragma unroll
  for (int i = 0; i < 64; i += 4)
    out[(size_t)(bj * 64 + r0 + i) * 1024 + bi * 64 + c] = tilebuf[c][r0 + i];
}

// ---------- fused QKV GEMM: 128x128 tile, BK=64, 512 threads (8 waves) ----------
// grid (x=row-tile 0..63, y=col-tile 0..7): linear id % 8 == row%8, so all 8
// col-tiles of one A row-tile land on ONE XCD (A fetched into a single L2).
__global__ __launch_bounds__(512) void gemm_qkv(
    const float* __restrict__ full, const float* __restrict__ ds,
    const unsigned short* __restrict__ WT,
    unsigned short* __restrict__ Qb, unsigned short* __restrict__ Kb,
    unsigned short* __restrict__ Vt) {
  __shared__ __align__(16) unsigned short As[128 * 64];
  __shared__ __align__(16) unsigned short Bs[128 * 64];
  int t = threadIdx.x;
  int lane = t & 63, wave = t >> 6;           // 8 waves
  int lrow = lane & 15, quad = lane >> 4;
  int by = blockIdx.x;                         // row-tile (XCD-swizzled)
  int colBase = blockIdx.y * 128;
  int wr = (wave & 3) * 32, wc = (wave >> 2) * 64;  // 4 row-groups x 2 col-groups
  int sw = lrow & 7;

  int sel = (by < 32) ? 0 : (by < 48 ? 1 : 2);
  const unsigned short* Wt = WT + (size_t)sel * (1u << 20);
  const float* Afp = (sel == 0) ? full : ds;
  size_t arow0 = (sel == 0) ? (size_t)by * 128
                            : (size_t)(by - (sel == 1 ? 32 : 48)) * 128;

  floatx4 acc[2][4];
#pragma unroll
  for (int mi = 0; mi < 2; ++mi)
#pragma unroll
    for (int ni = 0; ni < 4; ++ni) acc[mi][ni] = (floatx4){0.f, 0.f, 0.f, 0.f};

  for (int k0 = 0; k0 < 1024; k0 += 64) {
    __syncthreads();
#pragma unroll
    for (int it = 0; it < 2; ++it) {
      int linear = it * 512 + t;
      int row = linear >> 3;
      int cg = (linear & 7) ^ (row & 7);  // swizzled source chunk-col
      const float* p = Afp + (arow0 + row) * 1024 + k0 + cg * 8;
      floatx4 x = *(const floatx4*)p, y = *(const floatx4*)(p + 4);
      uint4v u = {pack_bf2(x[0], x[1]), pack_bf2(x[2], x[3]),
                  pack_bf2(y[0], y[1]), pack_bf2(y[2], y[3])};
      *(uint4v*)&As[linear * 8] = u;
      async16(Wt + (size_t)(colBase + row) * 1024 + k0 + cg * 8, Bs + linear * 8);
    }
    __syncthreads();

#pragma unroll
    for (int ks = 0; ks < 2; ++ks) {
      int fc = ((ks * 4 + quad) ^ sw) * 8;
      short8 af[2], bfr[4];
#pragma unroll
      for (int mi = 0; mi < 2; ++mi)
        af[mi] = *(const short8*)&As[(wr + mi * 16 + lrow) * 64 + fc];
#pragma unroll
      for (int ni = 0; ni < 4; ++ni)
        bfr[ni] = *(const short8*)&Bs[(wc + ni * 16 + lrow) * 64 + fc];
#pragma unroll
      for (int mi = 0; mi < 2; ++mi)
#pragma unroll
        for (int ni = 0; ni < 4; ++ni)
          acc[mi][ni] =
              __builtin_amdgcn_mfma_f32_16x16x32_bf16(af[mi], bfr[ni], acc[mi][ni], 0, 0, 0);
    }
  }

#pragma unroll
  for (int mi = 0; mi < 2; ++mi)
#pragma unroll
    for (int ni = 0; ni < 4; ++ni) {
      int col = colBase + wc + ni * 16 + lrow;
      if (sel == 2) {  // V: write transposed Vt[b][d=col][kv]
        size_t r0g = arow0 + wr + mi * 16 + quad * 4;
        size_t b = r0g >> 10, kv = r0g & 1023;
        short4v pk;
#pragma unroll
        for (int r = 0; r < 4; ++r) pk[r] = (short)f2bf(acc[mi][ni][r]);
        *(short4v*)&Vt[b * (1u << 20) + (size_t)col * 1024 + kv] = pk;
      } else {
        unsigned short* C = (sel == 0) ? Qb : Kb;
#pragma unroll
        for (int r = 0; r < 4; ++r) {
          size_t row = arow0 + wr + mi * 16 + quad * 4 + r;
          C[row * 1024 + col] = f2bf(acc[mi][ni][r]);
        }
      }
    }
}

// ---------- attention: 128 q-rows/block, 4 waves x 32 q-rows, dbuf, S^T form ----
// Each wave owns TWO 16-row q-tiles: K-frag and V-frag LDS reads amortize over
// 2x the MFMA work (5 ds_read_b128 per q-tile-chunk vs 9 in the 8-wave version).
#define PSTR 40
__global__ __launch_bounds__(256) void attn_kernel(
    const unsigned short* __restrict__ Q,   // [4096][1024] bf16
    const unsigned short* __restrict__ K,   // [2048][1024] bf16
    const unsigned short* __restrict__ V,   // Vt [B][1024 d][1024 kv] bf16
    unsigned short* __restrict__ O) {       // [4096][1024] bf16
  __shared__ __align__(16) unsigned short Ks[2][32 * 64];
  __shared__ __align__(16) unsigned short Vs[2][64 * 32];
  __shared__ __align__(16) unsigned short Pl[8][16 * PSTR];
  int t = threadIdx.x, lane = t & 63, wave = t >> 6;  // 4 waves
  int lrow = lane & 15, quad = lane >> 4;
  int bh = blockIdx.y, b = bh >> 4, h = bh & 15;
  int q0 = blockIdx.x * 128, qtile = q0 + wave * 32;
  int swk = lrow & 7, swv = (lrow >> 1) & 3;

  short8 qb[2][2];
#pragma unroll
  for (int mi = 0; mi < 2; ++mi) {
    const unsigned short* qp =
        Q + (size_t)(b * QN_ + qtile + mi * 16 + lrow) * 1024 + h * 64 + quad * 8;
    qb[mi][0] = *(const short8*)qp;
    qb[mi][1] = *(const short8*)(qp + 32);
  }

  // staging: every thread stages one 16B K-chunk and one 16B V-chunk
  int krow = t >> 3, kq = (t & 7) ^ (krow & 7);
  const unsigned short* ksrc =
      K + (size_t)(b * NDS_ + krow) * 1024 + h * 64 + kq * 8;
  int vrow = t >> 2, vq = (t & 3) ^ ((vrow >> 1) & 3);
  const unsigned short* vsrc =
      V + ((size_t)b * 1024 + h * 64 + vrow) * 1024 + vq * 8;

  int c0 = (q0 >= 1058) ? (((q0 - 1058) >> 5) + 1) : 0;
  async16(ksrc + (size_t)c0 * 32 * 1024, &Ks[0][t * 8]);
  async16(vsrc + c0 * 32, &Vs[0][t * 8]);
  const unsigned short* kpre = ksrc + (size_t)(c0 + 1) * 32 * 1024;
  const unsigned short* vpre = vsrc + (c0 + 1) * 32;

  floatx4 acc_o[2][4];
#pragma unroll
  for (int mi = 0; mi < 2; ++mi)
#pragma unroll
    for (int dt = 0; dt < 4; ++dt) acc_o[mi][dt] = (floatx4){0.f, 0.f, 0.f, 0.f};
  float den[2][2] = {{0.f, 0.f}, {0.f, 0.f}};
  unsigned short* P0 = Pl[wave * 2];
  unsigned short* P1 = Pl[wave * 2 + 1];
  int buf = 0;

  for (int c = c0; c < 32; ++c) {
    __syncthreads();  // chunk c staged; prior reads of buf^1 done
    if (c + 1 < 32) {
      async16(kpre, &Ks[buf ^ 1][t * 8]);
      async16(vpre, &Vs[buf ^ 1][t * 8]);
      kpre += 32 * 1024;
      vpre += 32;
    }
    int cb = c * 32;
    // wave-level skip: chunk fully masked for all 32 rows of this wave
    if (cb + 31 >= qtile - 1026) {
#pragma unroll
      for (int mi = 0; mi < 2; ++mi) {
        int qm = qtile + mi * 16;
        unsigned short* P = mi ? P1 : P0;
        bool fast2 = (cb >= qm + 13);                      // m == 2 everywhere
        bool fast1 = (cb <= qm - 34) && (cb >= qm - 1011); // m == 1 everywhere
        if (fast1 || fast2) {
          float bias = fast2 ? 1.f : 0.f;  // x2 folded into exponent
#pragma unroll
          for (int nt = 0; nt < 2; ++nt) {
            const unsigned short* kb = &Ks[buf][(nt * 16 + lrow) * 64];
            short8 ka0 = *(const short8*)(kb + (quad ^ swk) * 8);
            short8 ka1 = *(const short8*)(kb + ((quad + 4) ^ swk) * 8);
            floatx4 z = (floatx4){0.f, 0.f, 0.f, 0.f};
            z = __builtin_amdgcn_mfma_f32_16x16x32_bf16(ka0, qb[mi][0], z, 0, 0, 0);
            z = __builtin_amdgcn_mfma_f32_16x16x32_bf16(ka1, qb[mi][1], z, 0, 0, 0);
            float p[4];
#pragma unroll
            for (int r = 0; r < 4; ++r) {
              p[r] = __builtin_amdgcn_exp2f(fmaf(z[r], C_SC, bias));
              den[mi][nt] += p[r];
            }
            uint2v pw = {pack_bf2(p[0], p[1]), pack_bf2(p[2], p[3])};
            *(uint2v*)&P[lrow * PSTR + nt * 16 + quad * 4] = pw;
          }
        } else {
          int t1 = qm + lrow - 2, t2 = qm + lrow - 1026;
#pragma unroll
          for (int nt = 0; nt < 2; ++nt) {
            const unsigned short* kb = &Ks[buf][(nt * 16 + lrow) * 64];
            short8 ka0 = *(const short8*)(kb + (quad ^ swk) * 8);
            short8 ka1 = *(const short8*)(kb + ((quad + 4) ^ swk) * 8);
            floatx4 z = (floatx4){0.f, 0.f, 0.f, 0.f};
            z = __builtin_amdgcn_mfma_f32_16x16x32_bf16(ka0, qb[mi][0], z, 0, 0, 0);
            z = __builtin_amdgcn_mfma_f32_16x16x32_bf16(ka1, qb[mi][1], z, 0, 0, 0);
            float p[4];
#pragma unroll
            for (int r = 0; r < 4; ++r) {
              int j0 = cb + nt * 16 + quad * 4 + r;
              float m = (j0 >= t1 ? 1.f : 0.f) + (j0 >= t2 ? 1.f : 0.f);
              p[r] = m * __builtin_amdgcn_exp2f(z[r] * C_SC);
              den[mi][nt] += p[r];
            }
            uint2v pw = {pack_bf2(p[0], p[1]), pack_bf2(p[2], p[3])};
            *(uint2v*)&P[lrow * PSTR + nt * 16 + quad * 4] = pw;
          }
        }
      }
      short8 pa0 = *(const short8*)&P0[lrow * PSTR + quad * 8];
      short8 pa1 = *(const short8*)&P1[lrow * PSTR + quad * 8];
#pragma unroll
      for (int dt = 0; dt < 4; ++dt) {
        short8 vf =
            *(const short8*)&Vs[buf][(dt * 16 + lrow) * 32 + (quad ^ swv) * 8];
        acc_o[0][dt] = __builtin_amdgcn_mfma_f32_16x16x32_bf16(pa0, vf, acc_o[0][dt], 0, 0, 0);
        acc_o[1][dt] = __builtin_amdgcn_mfma_f32_16x16x32_bf16(pa1, vf, acc_o[1][dt], 0, 0, 0);
      }
    }
    buf ^= 1;
  }

#pragma unroll
  for (int mi = 0; mi < 2; ++mi) {
    float denom = den[mi][0] + den[mi][1];
    denom += __shfl_xor(denom, 16);
    denom += __shfl_xor(denom, 32);
    float dd[4];
#pragma unroll
    for (int r = 0; r < 4; ++r) dd[r] = __shfl(denom, quad * 4 + r);
#pragma unroll
    for (int dt = 0; dt < 4; ++dt)
#pragma unroll
      for (int r = 0; r < 4; ++r) {
        int i = qtile + mi * 16 + quad * 4 + r;
        int col = h * 64 + dt * 16 + lrow;
        O[(size_t)(b * QN_ + i) * 1024 + col] = f2bf(acc_o[mi][dt][r] / dd[r]);
      }
  }
}

// ---------- O GEMM: 64x128 tile, BK=64, 512 threads, XCD-swizzled grid ----------
__global__ __launch_bounds__(512) void gemm_o(
    const unsigned short* __restrict__ Ab, const unsigned short* __restrict__ WoT,
    const float* __restrict__ bo, float* __restrict__ out) {
  __shared__ __align__(16) unsigned short As[64 * 64];
  __shared__ __align__(16) unsigned short Bs[128 * 64];
  int t = threadIdx.x;
  int lane = t & 63, wave = t >> 6;  // 8 waves
  int lrow = lane & 15, quad = lane >> 4;
  size_t rowBase = (size_t)blockIdx.x * 64;   // row-tile (XCD-swizzled)
  int colBase = blockIdx.y * 128;
  int wr = (wave & 1) * 32, wc = (wave >> 1) * 32;  // 2 row x 4 col groups
  int sw = lrow & 7;

  floatx4 acc[2][2];
#pragma unroll
  for (int mi = 0; mi < 2; ++mi)
#pragma unroll
    for (int ni = 0; ni < 2; ++ni) acc[mi][ni] = (floatx4){0.f, 0.f, 0.f, 0.f};

  for (int k0 = 0; k0 < 1024; k0 += 64) {
    __syncthreads();
    {  // A: 64x64 = 512 chunks
      int row = t >> 3;
      int cg = (t & 7) ^ (row & 7);
      async16(Ab + (rowBase + row) * 1024 + k0 + cg * 8, As + t * 8);
    }
#pragma unroll
    for (int it = 0; it < 2; ++it) {  // B: 128x64 = 1024 chunks
      int linear = it * 512 + t;
      int row = linear >> 3;
      int cg = (linear & 7) ^ (row & 7);
      async16(WoT + (size_t)(colBase + row) * 1024 + k0 + cg * 8, Bs + linear * 8);
    }
    __syncthreads();

#pragma unroll
    for (int ks = 0; ks < 2; ++ks) {
      int fc = ((ks * 4 + quad) ^ sw) * 8;
      short8 af[2], bfr[2];
#pragma unroll
      for (int mi = 0; mi < 2; ++mi)
        af[mi] = *(const short8*)&As[(wr + mi * 16 + lrow) * 64 + fc];
#pragma unroll
      for (int ni = 0; ni < 2; ++ni)
        bfr[ni] = *(const short8*)&Bs[(wc + ni * 16 + lrow) * 64 + fc];
#pragma unroll
      for (int mi = 0; mi < 2; ++mi)
#pragma unroll
        for (int ni = 0; ni < 2; ++ni)
          acc[mi][ni] =
              __builtin_amdgcn_mfma_f32_16x16x32_bf16(af[mi], bfr[ni], acc[mi][ni], 0, 0, 0);
    }
  }

#pragma unroll
  for (int mi = 0; mi < 2; ++mi)
#pragma unroll
    for (int ni = 0; ni < 2; ++ni) {
      int col = colBase + wc + ni * 16 + lrow;
      float badd = bo[col];
#pragma unroll
      for (int r = 0; r < 4; ++r) {
        size_t row = rowBase + wr + mi * 16 + quad * 4 + r;
        out[row * 1024 + col] = acc[mi][ni][r] + badd;
      }
    }
}

// ---------- launch ----------
extern "C" void kernel_launch(void* const* d_in, const int* in_sizes, int n_in,
                              void* d_out, int out_size, void* d_ws, size_t ws_size,
                              hipStream_t stream) {
  const float* full = (const float*)d_in[0];  // [2,2048,1024] fp32
  const float* ds   = (const float*)d_in[1];  // [2,1024,1024] fp32
  const float* Wq   = (const float*)d_in[2];
  const float* Wk   = (const float*)d_in[3];
  const float* Wv   = (const float*)d_in[4];
  const float* Wo   = (const float*)d_in[5];
  const float* bo   = (const float*)d_in[6];
  float* out = (float*)d_out;

  // ws layout (halfwords), 32 MB total:
  unsigned short* ws = (unsigned short*)d_ws;
  unsigned short* Qb  = ws;                     // [0,4M)   4096x1024
  unsigned short* Kb  = ws + (4u << 20);        // [4M,6M)  2048x1024
  unsigned short* Vt  = ws + (6u << 20);        // [6M,8M)  [B][1024 d][1024 kv]
  unsigned short* Ab  = ws + (8u << 20);        // [8M,12M) 4096x1024
  unsigned short* WT  = ws + (12u << 20);       // [12M,16M) WqT WkT WvT WoT
  unsigned short* WoT = WT + 3u * (1u << 20);

  prep<<<1024, 256, 0, stream>>>(Wq, Wk, Wv, Wo, WT);
  gemm_qkv<<<dim3(64, 8), 512, 0, stream>>>(full, ds, WT, Qb, Kb, Vt);
  attn_kernel<<<dim3(QN_ / 128, B_ * H_), 256, 0, stream>>>(Qb, Kb, Vt, Ab);
  gemm_o<<<dim3(64, 8), 512, 0, stream>>>(Ab, WoT, bo, out);
}

// Round 2
// 174.591 us; speedup vs baseline: 1.0351x; 1.0351x over previous
//
#include <hip/hip_runtime.h>

// ---------- types / helpers ----------
typedef __attribute__((ext_vector_type(8))) short short8;    // 8 x bf16
typedef __attribute__((ext_vector_type(4))) short short4v;   // 4 x bf16
typedef __attribute__((ext_vector_type(4))) float floatx4;   // MFMA acc / 16B fp32
typedef __attribute__((ext_vector_type(4))) unsigned int uint4v;
typedef __attribute__((ext_vector_type(2))) unsigned int uint2v;

__device__ __forceinline__ unsigned short f2bf(float f) {
  unsigned u = __float_as_uint(f);
  u += 0x7FFFu + ((u >> 16) & 1u);
  return (unsigned short)(u >> 16);
}
// two fp32 -> dword [bf(f0)][bf(f1)] (validated R4+)
__device__ __forceinline__ unsigned pack_bf2(float f0, float f1) {
  unsigned a = __float_as_uint(f0) + 0x8000u;
  unsigned b = __float_as_uint(f1) + 0x8000u;
  return __builtin_amdgcn_perm(b, a, 0x07060302u);
}
__device__ __forceinline__ void async16(const unsigned short* g, unsigned short* l) {
  __builtin_amdgcn_global_load_lds(
      (const __attribute__((address_space(1))) unsigned int*)g,
      (__attribute__((address_space(3))) unsigned int*)l, 16, 0, 0);
}

#define B_   2
#define QN_  2048
#define NDS_ 1024
#define H_   16
// 0.125 * log2(e): exp(s/8) == exp2(s * C_SC)
#define C_SC 0.18033688011f

// ---------- prep: fp32 weights -> bf16 transposed (WT[n][k] = W[k][n]) ----------
__global__ __launch_bounds__(256) void prep(
    const float* __restrict__ Wq, const float* __restrict__ Wk,
    const float* __restrict__ Wv, const float* __restrict__ Wo,
    unsigned short* __restrict__ WT) {
  int bid = blockIdx.x;
  int z = bid >> 8, tile = bid & 255;
  const float* W = z == 0 ? Wq : z == 1 ? Wk : z == 2 ? Wv : Wo;
  unsigned short* out = WT + (size_t)z * (1u << 20);
  __shared__ unsigned short tilebuf[64][65];
  int bi = tile >> 4, bj = tile & 15;
  int c = threadIdx.x & 63, r0 = threadIdx.x >> 6;
#pragma unroll
  for (int i = 0; i < 64; i += 4)
    tilebuf[r0 + i][c] = f2bf(W[(size_t)(bi * 64 + r0 + i) * 1024 + bj * 64 + c]);
  __syncthreads();
#pragma unroll
  for (int i = 0; i < 64; i += 4)
    out[(size_t)(bj * 64 + r0 + i) * 1024 + bi * 64 + c] = tilebuf[c][r0 + i];
}

// ---------- fused QKV GEMM: 128x128 tile, BK=64, 512 threads (8 waves) ----------
// grid (x=row-tile 0..63, y=col-tile 0..7): linear id % 8 == row%8, so all 8
// col-tiles of one A row-tile land on ONE XCD (A fetched into a single L2).
__global__ __launch_bounds__(512) void gemm_qkv(
    const float* __restrict__ full, const float* __restrict__ ds,
    const unsigned short* __restrict__ WT,
    unsigned short* __restrict__ Qb, unsigned short* __restrict__ Kb,
    unsigned short* __restrict__ Vt) {
  __shared__ __align__(16) unsigned short As[128 * 64];
  __shared__ __align__(16) unsigned short Bs[128 * 64];
  int t = threadIdx.x;
  int lane = t & 63, wave = t >> 6;           // 8 waves
  int lrow = lane & 15, quad = lane >> 4;
  int by = blockIdx.x;                         // row-tile (XCD-swizzled)
  int colBase = blockIdx.y * 128;
  int wr = (wave & 3) * 32, wc = (wave >> 2) * 64;  // 4 row-groups x 2 col-groups
  int sw = lrow & 7;

  int sel = (by < 32) ? 0 : (by < 48 ? 1 : 2);
  const unsigned short* Wt = WT + (size_t)sel * (1u << 20);
  const float* Afp = (sel == 0) ? full : ds;
  size_t arow0 = (sel == 0) ? (size_t)by * 128
                            : (size_t)(by - (sel == 1 ? 32 : 48)) * 128;

  floatx4 acc[2][4];
#pragma unroll
  for (int mi = 0; mi < 2; ++mi)
#pragma unroll
    for (int ni = 0; ni < 4; ++ni) acc[mi][ni] = (floatx4){0.f, 0.f, 0.f, 0.f};

  for (int k0 = 0; k0 < 1024; k0 += 64) {
    __syncthreads();
#pragma unroll
    for (int it = 0; it < 2; ++it) {
      int linear = it * 512 + t;
      int row = linear >> 3;
      int cg = (linear & 7) ^ (row & 7);  // swizzled source chunk-col
      const float* p = Afp + (arow0 + row) * 1024 + k0 + cg * 8;
      floatx4 x = *(const floatx4*)p, y = *(const floatx4*)(p + 4);
      uint4v u = {pack_bf2(x[0], x[1]), pack_bf2(x[2], x[3]),
                  pack_bf2(y[0], y[1]), pack_bf2(y[2], y[3])};
      *(uint4v*)&As[linear * 8] = u;
      async16(Wt + (size_t)(colBase + row) * 1024 + k0 + cg * 8, Bs + linear * 8);
    }
    __syncthreads();

#pragma unroll
    for (int ks = 0; ks < 2; ++ks) {
      int fc = ((ks * 4 + quad) ^ sw) * 8;
      short8 af[2], bfr[4];
#pragma unroll
      for (int mi = 0; mi < 2; ++mi)
        af[mi] = *(const short8*)&As[(wr + mi * 16 + lrow) * 64 + fc];
#pragma unroll
      for (int ni = 0; ni < 4; ++ni)
        bfr[ni] = *(const short8*)&Bs[(wc + ni * 16 + lrow) * 64 + fc];
#pragma unroll
      for (int mi = 0; mi < 2; ++mi)
#pragma unroll
        for (int ni = 0; ni < 4; ++ni)
          acc[mi][ni] =
              __builtin_amdgcn_mfma_f32_16x16x32_bf16(af[mi], bfr[ni], acc[mi][ni], 0, 0, 0);
    }
  }

#pragma unroll
  for (int mi = 0; mi < 2; ++mi)
#pragma unroll
    for (int ni = 0; ni < 4; ++ni) {
      int col = colBase + wc + ni * 16 + lrow;
      if (sel == 2) {  // V: write transposed Vt[b][d=col][kv]
        size_t r0g = arow0 + wr + mi * 16 + quad * 4;
        size_t b = r0g >> 10, kv = r0g & 1023;
        short4v pk;
#pragma unroll
        for (int r = 0; r < 4; ++r) pk[r] = (short)f2bf(acc[mi][ni][r]);
        *(short4v*)&Vt[b * (1u << 20) + (size_t)col * 1024 + kv] = pk;
      } else {
        unsigned short* C = (sel == 0) ? Qb : Kb;
#pragma unroll
        for (int r = 0; r < 4; ++r) {
          size_t row = arow0 + wr + mi * 16 + quad * 4 + r;
          C[row * 1024 + col] = f2bf(acc[mi][ni][r]);
        }
      }
    }
}

// ---------- attention: 64 q-rows/block, 4 waves x 16 q-rows, dbuf, S^T form ----
// R1 post-mortem: kernel is latency/barrier-bound, not LDS-BW-bound. Keep the
// round-0 per-wave shape (16 rows) but use 4-wave blocks + grid (32,32):
// 4 independent blocks/CU x 4 waves = 16 waves/CU, so one block's per-chunk
// vmcnt-drain barrier overlaps with three other blocks' compute.
#define PSTR 40
__global__ __launch_bounds__(256) void attn_kernel(
    const unsigned short* __restrict__ Q,   // [4096][1024] bf16
    const unsigned short* __restrict__ K,   // [2048][1024] bf16
    const unsigned short* __restrict__ V,   // Vt [B][1024 d][1024 kv] bf16
    unsigned short* __restrict__ O) {       // [4096][1024] bf16
  __shared__ __align__(16) unsigned short Ks[2][32 * 64];
  __shared__ __align__(16) unsigned short Vs[2][64 * 32];
  __shared__ __align__(16) unsigned short Pl[4][16 * PSTR];
  int t = threadIdx.x, lane = t & 63, wave = t >> 6;  // 4 waves
  int lrow = lane & 15, quad = lane >> 4;
  int bh = blockIdx.y, b = bh >> 4, h = bh & 15;
  int q0 = blockIdx.x * 64, qtile = q0 + wave * 16;
  int swk = lrow & 7, swv = (lrow >> 1) & 3;

  const unsigned short* qp =
      Q + (size_t)(b * QN_ + qtile + lrow) * 1024 + h * 64 + quad * 8;
  short8 qb0 = *(const short8*)qp;
  short8 qb1 = *(const short8*)(qp + 32);

  // staging: every thread stages one 16B K-chunk and one 16B V-chunk
  int krow = t >> 3, kq = (t & 7) ^ (krow & 7);
  const unsigned short* ksrc =
      K + (size_t)(b * NDS_ + krow) * 1024 + h * 64 + kq * 8;
  int vrow = t >> 2, vq = (t & 3) ^ ((vrow >> 1) & 3);
  const unsigned short* vsrc =
      V + ((size_t)b * 1024 + h * 64 + vrow) * 1024 + vq * 8;

  int c0 = (q0 >= 1058) ? (((q0 - 1058) >> 5) + 1) : 0;
  async16(ksrc + (size_t)c0 * 32 * 1024, &Ks[0][t * 8]);
  async16(vsrc + c0 * 32, &Vs[0][t * 8]);
  const unsigned short* kpre = ksrc + (size_t)(c0 + 1) * 32 * 1024;
  const unsigned short* vpre = vsrc + (c0 + 1) * 32;

  floatx4 acc_o[4];
#pragma unroll
  for (int dt = 0; dt < 4; ++dt) acc_o[dt] = (floatx4){0.f, 0.f, 0.f, 0.f};
  float den0 = 0.f, den1 = 0.f;
  int t1 = qtile + lrow - 2, t2 = qtile + lrow - 1026;
  unsigned short* P = Pl[wave];
  int buf = 0;

  for (int c = c0; c < 32; ++c) {
    __syncthreads();  // chunk c staged; prior reads of buf^1 done
    if (c + 1 < 32) {
      async16(kpre, &Ks[buf ^ 1][t * 8]);
      async16(vpre, &Vs[buf ^ 1][t * 8]);
      kpre += 32 * 1024;
      vpre += 32;
    }
    int cb = c * 32;
    // wave-level skip: chunk fully masked for all 16 rows of this wave
    if (cb + 31 >= qtile - 1026) {
      bool fast2 = (cb >= qtile + 13);                          // m == 2 everywhere
      bool fast1 = (cb <= qtile - 34) && (cb >= qtile - 1011);  // m == 1 everywhere
      if (fast1 || fast2) {
        float bias = fast2 ? 1.f : 0.f;  // x2 folded into exponent
#pragma unroll
        for (int nt = 0; nt < 2; ++nt) {
          const unsigned short* kb = &Ks[buf][(nt * 16 + lrow) * 64];
          short8 ka0 = *(const short8*)(kb + (quad ^ swk) * 8);
          short8 ka1 = *(const short8*)(kb + ((quad + 4) ^ swk) * 8);
          floatx4 z = (floatx4){0.f, 0.f, 0.f, 0.f};
          z = __builtin_amdgcn_mfma_f32_16x16x32_bf16(ka0, qb0, z, 0, 0, 0);
          z = __builtin_amdgcn_mfma_f32_16x16x32_bf16(ka1, qb1, z, 0, 0, 0);
          float p[4];
#pragma unroll
          for (int r = 0; r < 4; ++r) {
            p[r] = __builtin_amdgcn_exp2f(fmaf(z[r], C_SC, bias));
            if (nt == 0) den0 += p[r]; else den1 += p[r];
          }
          uint2v pw = {pack_bf2(p[0], p[1]), pack_bf2(p[2], p[3])};
          *(uint2v*)&P[lrow * PSTR + nt * 16 + quad * 4] = pw;
        }
      } else {
#pragma unroll
        for (int nt = 0; nt < 2; ++nt) {
          const unsigned short* kb = &Ks[buf][(nt * 16 + lrow) * 64];
          short8 ka0 = *(const short8*)(kb + (quad ^ swk) * 8);
          short8 ka1 = *(const short8*)(kb + ((quad + 4) ^ swk) * 8);
          floatx4 z = (floatx4){0.f, 0.f, 0.f, 0.f};
          z = __builtin_amdgcn_mfma_f32_16x16x32_bf16(ka0, qb0, z, 0, 0, 0);
          z = __builtin_amdgcn_mfma_f32_16x16x32_bf16(ka1, qb1, z, 0, 0, 0);
          float p[4];
#pragma unroll
          for (int r = 0; r < 4; ++r) {
            int j0 = cb + nt * 16 + quad * 4 + r;
            float m = (j0 >= t1 ? 1.f : 0.f) + (j0 >= t2 ? 1.f : 0.f);
            p[r] = m * __builtin_amdgcn_exp2f(z[r] * C_SC);
            if (nt == 0) den0 += p[r]; else den1 += p[r];
          }
          uint2v pw = {pack_bf2(p[0], p[1]), pack_bf2(p[2], p[3])};
          *(uint2v*)&P[lrow * PSTR + nt * 16 + quad * 4] = pw;
        }
      }
      short8 pa = *(const short8*)&P[lrow * PSTR + quad * 8];
#pragma unroll
      for (int dt = 0; dt < 4; ++dt) {
        short8 vf =
            *(const short8*)&Vs[buf][(dt * 16 + lrow) * 32 + (quad ^ swv) * 8];
        acc_o[dt] = __builtin_amdgcn_mfma_f32_16x16x32_bf16(pa, vf, acc_o[dt], 0, 0, 0);
      }
    }
    buf ^= 1;
  }
  float denom = den0 + den1;
  denom += __shfl_xor(denom, 16);
  denom += __shfl_xor(denom, 32);
  float dd[4];
#pragma unroll
  for (int r = 0; r < 4; ++r) dd[r] = __shfl(denom, quad * 4 + r);
#pragma unroll
  for (int dt = 0; dt < 4; ++dt)
#pragma unroll
    for (int r = 0; r < 4; ++r) {
      int i = qtile + quad * 4 + r;
      int col = h * 64 + dt * 16 + lrow;
      O[(size_t)(b * QN_ + i) * 1024 + col] = f2bf(acc_o[dt][r] / dd[r]);
    }
}

// ---------- O GEMM: 64x128 tile, BK=64, 512 threads, XCD-swizzled grid ----------
__global__ __launch_bounds__(512) void gemm_o(
    const unsigned short* __restrict__ Ab, const unsigned short* __restrict__ WoT,
    const float* __restrict__ bo, float* __restrict__ out) {
  __shared__ __align__(16) unsigned short As[64 * 64];
  __shared__ __align__(16) unsigned short Bs[128 * 64];
  int t = threadIdx.x;
  int lane = t & 63, wave = t >> 6;  // 8 waves
  int lrow = lane & 15, quad = lane >> 4;
  size_t rowBase = (size_t)blockIdx.x * 64;   // row-tile (XCD-swizzled)
  int colBase = blockIdx.y * 128;
  int wr = (wave & 1) * 32, wc = (wave >> 1) * 32;  // 2 row x 4 col groups
  int sw = lrow & 7;

  floatx4 acc[2][2];
#pragma unroll
  for (int mi = 0; mi < 2; ++mi)
#pragma unroll
    for (int ni = 0; ni < 2; ++ni) acc[mi][ni] = (floatx4){0.f, 0.f, 0.f, 0.f};

  for (int k0 = 0; k0 < 1024; k0 += 64) {
    __syncthreads();
    {  // A: 64x64 = 512 chunks
      int row = t >> 3;
      int cg = (t & 7) ^ (row & 7);
      async16(Ab + (rowBase + row) * 1024 + k0 + cg * 8, As + t * 8);
    }
#pragma unroll
    for (int it = 0; it < 2; ++it) {  // B: 128x64 = 1024 chunks
      int linear = it * 512 + t;
      int row = linear >> 3;
      int cg = (linear & 7) ^ (row & 7);
      async16(WoT + (size_t)(colBase + row) * 1024 + k0 + cg * 8, Bs + linear * 8);
    }
    __syncthreads();

#pragma unroll
    for (int ks = 0; ks < 2; ++ks) {
      int fc = ((ks * 4 + quad) ^ sw) * 8;
      short8 af[2], bfr[2];
#pragma unroll
      for (int mi = 0; mi < 2; ++mi)
        af[mi] = *(const short8*)&As[(wr + mi * 16 + lrow) * 64 + fc];
#pragma unroll
      for (int ni = 0; ni < 2; ++ni)
        bfr[ni] = *(const short8*)&Bs[(wc + ni * 16 + lrow) * 64 + fc];
#pragma unroll
      for (int mi = 0; mi < 2; ++mi)
#pragma unroll
        for (int ni = 0; ni < 2; ++ni)
          acc[mi][ni] =
              __builtin_amdgcn_mfma_f32_16x16x32_bf16(af[mi], bfr[ni], acc[mi][ni], 0, 0, 0);
    }
  }

#pragma unroll
  for (int mi = 0; mi < 2; ++mi)
#pragma unroll
    for (int ni = 0; ni < 2; ++ni) {
      int col = colBase + wc + ni * 16 + lrow;
      float badd = bo[col];
#pragma unroll
      for (int r = 0; r < 4; ++r) {
        size_t row = rowBase + wr + mi * 16 + quad * 4 + r;
        out[row * 1024 + col] = acc[mi][ni][r] + badd;
      }
    }
}

// ---------- launch ----------
extern "C" void kernel_launch(void* const* d_in, const int* in_sizes, int n_in,
                              void* d_out, int out_size, void* d_ws, size_t ws_size,
                              hipStream_t stream) {
  const float* full = (const float*)d_in[0];  // [2,2048,1024] fp32
  const float* ds   = (const float*)d_in[1];  // [2,1024,1024] fp32
  const float* Wq   = (const float*)d_in[2];
  const float* Wk   = (const float*)d_in[3];
  const float* Wv   = (const float*)d_in[4];
  const float* Wo   = (const float*)d_in[5];
  const float* bo   = (const float*)d_in[6];
  float* out = (float*)d_out;

  // ws layout (halfwords), 32 MB total:
  unsigned short* ws = (unsigned short*)d_ws;
  unsigned short* Qb  = ws;                     // [0,4M)   4096x1024
  unsigned short* Kb  = ws + (4u << 20);        // [4M,6M)  2048x1024
  unsigned short* Vt  = ws + (6u << 20);        // [6M,8M)  [B][1024 d][1024 kv]
  unsigned short* Ab  = ws + (8u << 20);        // [8M,12M) 4096x1024
  unsigned short* WT  = ws + (12u << 20);       // [12M,16M) WqT WkT WvT WoT
  unsigned short* WoT = WT + 3u * (1u << 20);

  prep<<<1024, 256, 0, stream>>>(Wq, Wk, Wv, Wo, WT);
  gemm_qkv<<<dim3(64, 8), 512, 0, stream>>>(full, ds, WT, Qb, Kb, Vt);
  attn_kernel<<<dim3(QN_ / 64, B_ * H_), 256, 0, stream>>>(Qb, Kb, Vt, Ab);
  gemm_o<<<dim3(64, 8), 512, 0, stream>>>(Ab, WoT, bo, out);
}

// Round 3
// 168.889 us; speedup vs baseline: 1.0700x; 1.0338x over previous
//
#include <hip/hip_runtime.h>

// ---------- types / helpers ----------
typedef __attribute__((ext_vector_type(8))) short short8;    // 8 x bf16
typedef __attribute__((ext_vector_type(4))) short short4v;   // 4 x bf16
typedef __attribute__((ext_vector_type(4))) float floatx4;   // MFMA acc / 16B fp32
typedef __attribute__((ext_vector_type(4))) unsigned int uint4v;
typedef __attribute__((ext_vector_type(2))) unsigned int uint2v;

__device__ __forceinline__ unsigned short f2bf(float f) {
  unsigned u = __float_as_uint(f);
  u += 0x7FFFu + ((u >> 16) & 1u);
  return (unsigned short)(u >> 16);
}
// two fp32 -> dword [bf(f0)][bf(f1)] (validated R4+)
__device__ __forceinline__ unsigned pack_bf2(float f0, float f1) {
  unsigned a = __float_as_uint(f0) + 0x8000u;
  unsigned b = __float_as_uint(f1) + 0x8000u;
  return __builtin_amdgcn_perm(b, a, 0x07060302u);
}
__device__ __forceinline__ void async16(const unsigned short* g, unsigned short* l) {
  __builtin_amdgcn_global_load_lds(
      (const __attribute__((address_space(1))) unsigned int*)g,
      (__attribute__((address_space(3))) unsigned int*)l, 16, 0, 0);
}

#define B_   2
#define QN_  2048
#define NDS_ 1024
#define H_   16
// 0.125 * log2(e): exp(s/8) == exp2(s * C_SC)
#define C_SC 0.18033688011f

// ---------- prep: fp32 weights -> bf16 transposed (WT[n][k] = W[k][n]) ----------
__global__ __launch_bounds__(256) void prep(
    const float* __restrict__ Wq, const float* __restrict__ Wk,
    const float* __restrict__ Wv, const float* __restrict__ Wo,
    unsigned short* __restrict__ WT) {
  int bid = blockIdx.x;
  int z = bid >> 8, tile = bid & 255;
  const float* W = z == 0 ? Wq : z == 1 ? Wk : z == 2 ? Wv : Wo;
  unsigned short* out = WT + (size_t)z * (1u << 20);
  __shared__ unsigned short tilebuf[64][65];
  int bi = tile >> 4, bj = tile & 15;
  int c = threadIdx.x & 63, r0 = threadIdx.x >> 6;
#pragma unroll
  for (int i = 0; i < 64; i += 4)
    tilebuf[r0 + i][c] = f2bf(W[(size_t)(bi * 64 + r0 + i) * 1024 + bj * 64 + c]);
  __syncthreads();
#pragma unroll
  for (int i = 0; i < 64; i += 4)
    out[(size_t)(bj * 64 + r0 + i) * 1024 + bi * 64 + c] = tilebuf[c][r0 + i];
}

// ---------- fused QKV GEMM: 128x128 tile, BK=64, 512 threads (8 waves) ----------
__global__ __launch_bounds__(512) void gemm_qkv(
    const float* __restrict__ full, const float* __restrict__ ds,
    const unsigned short* __restrict__ WT,
    unsigned short* __restrict__ Qb, unsigned short* __restrict__ Kb,
    unsigned short* __restrict__ Vt) {
  __shared__ __align__(16) unsigned short As[128 * 64];
  __shared__ __align__(16) unsigned short Bs[128 * 64];
  int t = threadIdx.x;
  int lane = t & 63, wave = t >> 6;           // 8 waves
  int lrow = lane & 15, quad = lane >> 4;
  int by = blockIdx.x;                         // row-tile (XCD-swizzled)
  int colBase = blockIdx.y * 128;
  int wr = (wave & 3) * 32, wc = (wave >> 2) * 64;  // 4 row-groups x 2 col-groups
  int sw = lrow & 7;

  int sel = (by < 32) ? 0 : (by < 48 ? 1 : 2);
  const unsigned short* Wt = WT + (size_t)sel * (1u << 20);
  const float* Afp = (sel == 0) ? full : ds;
  size_t arow0 = (sel == 0) ? (size_t)by * 128
                            : (size_t)(by - (sel == 1 ? 32 : 48)) * 128;

  floatx4 acc[2][4];
#pragma unroll
  for (int mi = 0; mi < 2; ++mi)
#pragma unroll
    for (int ni = 0; ni < 4; ++ni) acc[mi][ni] = (floatx4){0.f, 0.f, 0.f, 0.f};

  for (int k0 = 0; k0 < 1024; k0 += 64) {
    __syncthreads();
#pragma unroll
    for (int it = 0; it < 2; ++it) {
      int linear = it * 512 + t;
      int row = linear >> 3;
      int cg = (linear & 7) ^ (row & 7);  // swizzled source chunk-col
      const float* p = Afp + (arow0 + row) * 1024 + k0 + cg * 8;
      floatx4 x = *(const floatx4*)p, y = *(const floatx4*)(p + 4);
      uint4v u = {pack_bf2(x[0], x[1]), pack_bf2(x[2], x[3]),
                  pack_bf2(y[0], y[1]), pack_bf2(y[2], y[3])};
      *(uint4v*)&As[linear * 8] = u;
      async16(Wt + (size_t)(colBase + row) * 1024 + k0 + cg * 8, Bs + linear * 8);
    }
    __syncthreads();

#pragma unroll
    for (int ks = 0; ks < 2; ++ks) {
      int fc = ((ks * 4 + quad) ^ sw) * 8;
      short8 af[2], bfr[4];
#pragma unroll
      for (int mi = 0; mi < 2; ++mi)
        af[mi] = *(const short8*)&As[(wr + mi * 16 + lrow) * 64 + fc];
#pragma unroll
      for (int ni = 0; ni < 4; ++ni)
        bfr[ni] = *(const short8*)&Bs[(wc + ni * 16 + lrow) * 64 + fc];
#pragma unroll
      for (int mi = 0; mi < 2; ++mi)
#pragma unroll
        for (int ni = 0; ni < 4; ++ni)
          acc[mi][ni] =
              __builtin_amdgcn_mfma_f32_16x16x32_bf16(af[mi], bfr[ni], acc[mi][ni], 0, 0, 0);
    }
  }

#pragma unroll
  for (int mi = 0; mi < 2; ++mi)
#pragma unroll
    for (int ni = 0; ni < 4; ++ni) {
      int col = colBase + wc + ni * 16 + lrow;
      if (sel == 2) {  // V: write transposed Vt[b][d=col][kv]
        size_t r0g = arow0 + wr + mi * 16 + quad * 4;
        size_t b = r0g >> 10, kv = r0g & 1023;
        short4v pk;
#pragma unroll
        for (int r = 0; r < 4; ++r) pk[r] = (short)f2bf(acc[mi][ni][r]);
        *(short4v*)&Vt[b * (1u << 20) + (size_t)col * 1024 + kv] = pk;
      } else {
        unsigned short* C = (sel == 0) ? Qb : Kb;
#pragma unroll
        for (int r = 0; r < 4; ++r) {
          size_t row = arow0 + wr + mi * 16 + quad * 4 + r;
          C[row * 1024 + col] = f2bf(acc[mi][ni][r]);
        }
      }
    }
}

// ---------- attention: R0 topology (512 thr, 8 waves x 16 q-rows, grid 16x32),
// KV chunk doubled to 64 (16 iterations): half the barrier/vmcnt-drain events,
// 2x MFMA work per barrier. Mask/softmax evaluated per 32-kv half (identical
// compute volume to R0). P double-buffered per wave (no WAR between halves).
#define PSTR 40
__global__ __launch_bounds__(512) void attn_kernel(
    const unsigned short* __restrict__ Q,   // [4096][1024] bf16
    const unsigned short* __restrict__ K,   // [2048][1024] bf16
    const unsigned short* __restrict__ V,   // Vt [B][1024 d][1024 kv] bf16
    unsigned short* __restrict__ O) {       // [4096][1024] bf16
  __shared__ __align__(16) unsigned short Ks[2][64 * 64];
  __shared__ __align__(16) unsigned short Vs[2][64 * 64];
  __shared__ __align__(16) unsigned short Pl[8][2][16 * PSTR];
  int t = threadIdx.x, lane = t & 63, wave = t >> 6;  // 8 waves
  int lrow = lane & 15, quad = lane >> 4;
  int bh = blockIdx.y, b = bh >> 4, h = bh & 15;
  int q0 = blockIdx.x * 128, qtile = q0 + wave * 16;
  int swk = lrow & 7;

  const unsigned short* qp =
      Q + (size_t)(b * QN_ + qtile + lrow) * 1024 + h * 64 + quad * 8;
  short8 qb0 = *(const short8*)qp;
  short8 qb1 = *(const short8*)(qp + 32);

  // staging: each thread stages one 16B K granule + one 16B V granule per chunk
  int krow = t >> 3, kg = (t & 7) ^ (krow & 7);
  const unsigned short* ksrc =
      K + (size_t)(b * NDS_ + krow) * 1024 + h * 64 + kg * 8;
  int vrow = t >> 3, vg = (t & 7) ^ (vrow & 7);
  const unsigned short* vsrc =
      V + ((size_t)b * 1024 + h * 64 + vrow) * 1024 + vg * 8;

  int c0 = (q0 >= 1090) ? (((q0 - 1090) >> 6) + 1) : 0;
  async16(ksrc + (size_t)c0 * 64 * 1024, &Ks[0][t * 8]);
  async16(vsrc + c0 * 64, &Vs[0][t * 8]);
  const unsigned short* kpre = ksrc + (size_t)(c0 + 1) * 64 * 1024;
  const unsigned short* vpre = vsrc + (c0 + 1) * 64;

  floatx4 acc_o[4];
#pragma unroll
  for (int dt = 0; dt < 4; ++dt) acc_o[dt] = (floatx4){0.f, 0.f, 0.f, 0.f};
  float den0 = 0.f, den1 = 0.f;
  int t1 = qtile + lrow - 2, t2 = qtile + lrow - 1026;
  int buf = 0;

  for (int c = c0; c < 16; ++c) {
    __syncthreads();  // chunk c staged; prior reads of buf^1 done
    if (c + 1 < 16) {
      async16(kpre, &Ks[buf ^ 1][t * 8]);
      async16(vpre, &Vs[buf ^ 1][t * 8]);
      kpre += 64 * 1024;
      vpre += 64;
    }
    int cb = c * 64;
#pragma unroll
    for (int hf = 0; hf < 2; ++hf) {
      int hb = cb + hf * 32;
      if (hb + 31 < qtile - 1026) continue;  // half fully masked for this wave
      unsigned short* P = Pl[wave][hf];
      bool fast2 = (hb >= qtile + 13);                          // m == 2 everywhere
      bool fast1 = (hb <= qtile - 34) && (hb >= qtile - 1011);  // m == 1 everywhere
      if (fast1 || fast2) {
        float bias = fast2 ? 1.f : 0.f;  // x2 folded into exponent
#pragma unroll
        for (int nt = 0; nt < 2; ++nt) {
          const unsigned short* kb = &Ks[buf][(hf * 32 + nt * 16 + lrow) * 64];
          short8 ka0 = *(const short8*)(kb + (quad ^ swk) * 8);
          short8 ka1 = *(const short8*)(kb + ((quad + 4) ^ swk) * 8);
          floatx4 z = (floatx4){0.f, 0.f, 0.f, 0.f};
          z = __builtin_amdgcn_mfma_f32_16x16x32_bf16(ka0, qb0, z, 0, 0, 0);
          z = __builtin_amdgcn_mfma_f32_16x16x32_bf16(ka1, qb1, z, 0, 0, 0);
          float p[4];
#pragma unroll
          for (int r = 0; r < 4; ++r) {
            p[r] = __builtin_amdgcn_exp2f(fmaf(z[r], C_SC, bias));
            if (nt == 0) den0 += p[r]; else den1 += p[r];
          }
          uint2v pw = {pack_bf2(p[0], p[1]), pack_bf2(p[2], p[3])};
          *(uint2v*)&P[lrow * PSTR + nt * 16 + quad * 4] = pw;
        }
      } else {
#pragma unroll
        for (int nt = 0; nt < 2; ++nt) {
          const unsigned short* kb = &Ks[buf][(hf * 32 + nt * 16 + lrow) * 64];
          short8 ka0 = *(const short8*)(kb + (quad ^ swk) * 8);
          short8 ka1 = *(const short8*)(kb + ((quad + 4) ^ swk) * 8);
          floatx4 z = (floatx4){0.f, 0.f, 0.f, 0.f};
          z = __builtin_amdgcn_mfma_f32_16x16x32_bf16(ka0, qb0, z, 0, 0, 0);
          z = __builtin_amdgcn_mfma_f32_16x16x32_bf16(ka1, qb1, z, 0, 0, 0);
          float p[4];
#pragma unroll
          for (int r = 0; r < 4; ++r) {
            int j0 = hb + nt * 16 + quad * 4 + r;
            float m = (j0 >= t1 ? 1.f : 0.f) + (j0 >= t2 ? 1.f : 0.f);
            p[r] = m * __builtin_amdgcn_exp2f(z[r] * C_SC);
            if (nt == 0) den0 += p[r]; else den1 += p[r];
          }
          uint2v pw = {pack_bf2(p[0], p[1]), pack_bf2(p[2], p[3])};
          *(uint2v*)&P[lrow * PSTR + nt * 16 + quad * 4] = pw;
        }
      }
      short8 pa = *(const short8*)&P[lrow * PSTR + quad * 8];
#pragma unroll
      for (int dt = 0; dt < 4; ++dt) {
        int g = (quad + 4 * hf) ^ swk;  // kv granule within 64-kv chunk
        short8 vf = *(const short8*)&Vs[buf][(dt * 16 + lrow) * 64 + g * 8];
        acc_o[dt] = __builtin_amdgcn_mfma_f32_16x16x32_bf16(pa, vf, acc_o[dt], 0, 0, 0);
      }
    }
    buf ^= 1;
  }
  float denom = den0 + den1;
  denom += __shfl_xor(denom, 16);
  denom += __shfl_xor(denom, 32);
  float dd[4];
#pragma unroll
  for (int r = 0; r < 4; ++r) dd[r] = __shfl(denom, quad * 4 + r);
#pragma unroll
  for (int dt = 0; dt < 4; ++dt)
#pragma unroll
    for (int r = 0; r < 4; ++r) {
      int i = qtile + quad * 4 + r;
      int col = h * 64 + dt * 16 + lrow;
      O[(size_t)(b * QN_ + i) * 1024 + col] = f2bf(acc_o[dt][r] / dd[r]);
    }
}

// ---------- O GEMM: 64x128 tile, BK=64, 512 threads, XCD-swizzled grid ----------
__global__ __launch_bounds__(512) void gemm_o(
    const unsigned short* __restrict__ Ab, const unsigned short* __restrict__ WoT,
    const float* __restrict__ bo, float* __restrict__ out) {
  __shared__ __align__(16) unsigned short As[64 * 64];
  __shared__ __align__(16) unsigned short Bs[128 * 64];
  int t = threadIdx.x;
  int lane = t & 63, wave = t >> 6;  // 8 waves
  int lrow = lane & 15, quad = lane >> 4;
  size_t rowBase = (size_t)blockIdx.x * 64;   // row-tile (XCD-swizzled)
  int colBase = blockIdx.y * 128;
  int wr = (wave & 1) * 32, wc = (wave >> 1) * 32;  // 2 row x 4 col groups
  int sw = lrow & 7;

  floatx4 acc[2][2];
#pragma unroll
  for (int mi = 0; mi < 2; ++mi)
#pragma unroll
    for (int ni = 0; ni < 2; ++ni) acc[mi][ni] = (floatx4){0.f, 0.f, 0.f, 0.f};

  for (int k0 = 0; k0 < 1024; k0 += 64) {
    __syncthreads();
    {  // A: 64x64 = 512 chunks
      int row = t >> 3;
      int cg = (t & 7) ^ (row & 7);
      async16(Ab + (rowBase + row) * 1024 + k0 + cg * 8, As + t * 8);
    }
#pragma unroll
    for (int it = 0; it < 2; ++it) {  // B: 128x64 = 1024 chunks
      int linear = it * 512 + t;
      int row = linear >> 3;
      int cg = (linear & 7) ^ (row & 7);
      async16(WoT + (size_t)(colBase + row) * 1024 + k0 + cg * 8, Bs + linear * 8);
    }
    __syncthreads();

#pragma unroll
    for (int ks = 0; ks < 2; ++ks) {
      int fc = ((ks * 4 + quad) ^ sw) * 8;
      short8 af[2], bfr[2];
#pragma unroll
      for (int mi = 0; mi < 2; ++mi)
        af[mi] = *(const short8*)&As[(wr + mi * 16 + lrow) * 64 + fc];
#pragma unroll
      for (int ni = 0; ni < 2; ++ni)
        bfr[ni] = *(const short8*)&Bs[(wc + ni * 16 + lrow) * 64 + fc];
#pragma unroll
      for (int mi = 0; mi < 2; ++mi)
#pragma unroll
        for (int ni = 0; ni < 2; ++ni)
          acc[mi][ni] =
              __builtin_amdgcn_mfma_f32_16x16x32_bf16(af[mi], bfr[ni], acc[mi][ni], 0, 0, 0);
    }
  }

#pragma unroll
  for (int mi = 0; mi < 2; ++mi)
#pragma unroll
    for (int ni = 0; ni < 2; ++ni) {
      int col = colBase + wc + ni * 16 + lrow;
      float badd = bo[col];
#pragma unroll
      for (int r = 0; r < 4; ++r) {
        size_t row = rowBase + wr + mi * 16 + quad * 4 + r;
        out[row * 1024 + col] = acc[mi][ni][r] + badd;
      }
    }
}

// ---------- launch ----------
extern "C" void kernel_launch(void* const* d_in, const int* in_sizes, int n_in,
                              void* d_out, int out_size, void* d_ws, size_t ws_size,
                              hipStream_t stream) {
  const float* full = (const float*)d_in[0];  // [2,2048,1024] fp32
  const float* ds   = (const float*)d_in[1];  // [2,1024,1024] fp32
  const float* Wq   = (const float*)d_in[2];
  const float* Wk   = (const float*)d_in[3];
  const float* Wv   = (const float*)d_in[4];
  const float* Wo   = (const float*)d_in[5];
  const float* bo   = (const float*)d_in[6];
  float* out = (float*)d_out;

  // ws layout (halfwords), 32 MB total:
  unsigned short* ws = (unsigned short*)d_ws;
  unsigned short* Qb  = ws;                     // [0,4M)   4096x1024
  unsigned short* Kb  = ws + (4u << 20);        // [4M,6M)  2048x1024
  unsigned short* Vt  = ws + (6u << 20);        // [6M,8M)  [B][1024 d][1024 kv]
  unsigned short* Ab  = ws + (8u << 20);        // [8M,12M) 4096x1024
  unsigned short* WT  = ws + (12u << 20);       // [12M,16M) WqT WkT WvT WoT
  unsigned short* WoT = WT + 3u * (1u << 20);

  prep<<<1024, 256, 0, stream>>>(Wq, Wk, Wv, Wo, WT);
  gemm_qkv<<<dim3(64, 8), 512, 0, stream>>>(full, ds, WT, Qb, Kb, Vt);
  attn_kernel<<<dim3(QN_ / 128, B_ * H_), 512, 0, stream>>>(Qb, Kb, Vt, Ab);
  gemm_o<<<dim3(64, 8), 512, 0, stream>>>(Ab, WoT, bo, out);
}